// Round 7
// baseline (119.227 us; speedup 1.0000x reference)
//
#include <hip/hip_runtime.h>

#define IN_F   1024
#define OUT_F  1024
#define BATCHN 4096
#define KDIM   9216   // 9 * 1024 (t-plane layout: k = t*1024 + i)

using bf16x8 = __attribute__((ext_vector_type(8))) __bf16;
using f32x4  = __attribute__((ext_vector_type(4))) float;

__device__ __forceinline__ unsigned short f2bf(float f) {
  union { float f; unsigned int u; } v; v.f = f;
  unsigned int u = v.u;
  unsigned int r = (u + 0x7FFFu + ((u >> 16) & 1u)) >> 16;  // RNE
  return (unsigned short)r;
}

__device__ __forceinline__ float bf2f(unsigned short h) {
  union { unsigned int u; float f; } v; v.u = ((unsigned int)h) << 16;
  return v.f;
}

__device__ __forceinline__ void async_load16(const void* g, void* l) {
  __builtin_amdgcn_global_load_lds(
      (__attribute__((address_space(1))) void*)(g),
      (__attribute__((address_space(3))) void*)(l),
      16, 0, 0);
}

// ---------------------------------------------------------------------------
// Ã[b][t*1024+i] : t=0 -> silu(x[b,i]); t=1..8 -> cubic B-spline basis values
// ---------------------------------------------------------------------------
__global__ __launch_bounds__(256) void kan_prep_a(const float* __restrict__ x,
                                                  const float* __restrict__ grid,
                                                  unsigned short* __restrict__ A) {
  int idx = blockIdx.x * 256 + threadIdx.x;      // b*1024 + i, i fastest
  int i = idx & 1023;
  float xv = x[idx];
  float sil = xv / (1.0f + __expf(-xv));

  const float* g = grid + i * 12;
  float t[12];
#pragma unroll
  for (int j = 0; j < 12; ++j) t[j] = g[j];

  float B[11];
#pragma unroll
  for (int j = 0; j < 11; ++j) B[j] = (xv >= t[j] && xv < t[j + 1]) ? 1.0f : 0.0f;

  float inv_h = 1.0f / (t[4] - t[3]);            // uniform spacing
  const float invp[3] = {inv_h, inv_h * 0.5f, inv_h * (1.0f / 3.0f)};
#pragma unroll
  for (int p = 1; p <= 3; ++p) {
    float ip = invp[p - 1];
#pragma unroll
    for (int j = 0; j + p < 11; ++j)
      B[j] = (xv - t[j]) * ip * B[j] + (t[j + p + 1] - xv) * ip * B[j + 1];
  }

  size_t base = (size_t)(idx >> 10) * KDIM + i;
  A[base] = f2bf(sil);                            // t = 0 plane
#pragma unroll
  for (int k = 0; k < 8; ++k) A[base + (size_t)(k + 1) * 1024] = f2bf(B[k]);
}

// ---------------------------------------------------------------------------
// W_T[o][t*1024+i] = t==0 ? scale_base[i,o] : scale_sp[i,o]*coef[i,o,t-1]
// ---------------------------------------------------------------------------
__global__ __launch_bounds__(256) void kan_prep_w(const float* __restrict__ sb,
                                                  const float* __restrict__ ssp,
                                                  const float* __restrict__ coef,
                                                  unsigned short* __restrict__ WT) {
  __shared__ unsigned short lds[9][32][33];
  int i0 = (blockIdx.x >> 5) * 32, o0 = (blockIdx.x & 31) * 32;
  int tid = threadIdx.x;
#pragma unroll
  for (int r = 0; r < 4; ++r) {
    int idx = r * 256 + tid;
    int ii = idx >> 5, oo = idx & 31;
    int io = (i0 + ii) * 1024 + (o0 + oo);
    float b = sb[io], s = ssp[io];
    const float4* cp = (const float4*)(coef + (size_t)io * 8);
    float4 c0 = cp[0], c1 = cp[1];
    lds[0][ii][oo] = f2bf(b);
    lds[1][ii][oo] = f2bf(s * c0.x);
    lds[2][ii][oo] = f2bf(s * c0.y);
    lds[3][ii][oo] = f2bf(s * c0.z);
    lds[4][ii][oo] = f2bf(s * c0.w);
    lds[5][ii][oo] = f2bf(s * c1.x);
    lds[6][ii][oo] = f2bf(s * c1.y);
    lds[7][ii][oo] = f2bf(s * c1.z);
    lds[8][ii][oo] = f2bf(s * c1.w);
  }
  __syncthreads();
#pragma unroll
  for (int r = 0; r < 4; ++r) {
    int idx = r * 256 + tid;
    int oo = idx >> 5, ii = idx & 31;
    size_t rowbase = (size_t)(o0 + oo) * KDIM + i0 + ii;
#pragma unroll
    for (int tp = 0; tp < 9; ++tp) WT[rowbase + tp * 1024] = lds[tp][ii][oo];
  }
}

// ---------------------------------------------------------------------------
// GEMM split-K=4, m201-style 4-phase engine with K-half-tile staging.
// BM=BN=256, BK=64, 512 thr / 8 waves (2Mx4N, 128x64 out per wave).
// LDS 128 KiB: panels {A,B}x{ks0,ks1}, each 256x32 (16 KiB), double-buffered.
// Per slice, 4 phases (ks,mq), each: {ds_read 8|4 b128 ; stage ONE half-tile
// (2 gload) ; [vmcnt(4) at ph1/ph3] ; barrier ; lgkmcnt(0) ; 16 MFMA ;
// barrier}. vmcnt(4) FIFO proof: queue = [pair needed next phase (4 loads),
// pair just issued (4)] -> wait-to-4 lands exactly the needed pair; the
// following barrier makes each wave's own vmcnt block-wide.
// ---------------------------------------------------------------------------
#define BM 256
#define BN 256
#define BK 64
#define KQ     (KDIM / 4)    // 2304 per split-K group
#define NSL    (KQ / BK)     // 36
#define PAN    8192          // 16 KiB panel = 256 rows x 32 elems (shorts)

__global__ __launch_bounds__(512, 2) void kan_gemm(const unsigned short* __restrict__ A,
                                                   const unsigned short* __restrict__ BT,
                                                   float* __restrict__ C,
                                                   unsigned short* __restrict__ P) {
  extern __shared__ unsigned short lds[];
  unsigned short* As = lds;                 // [dbuf][ks] -> 4 * PAN
  unsigned short* Bs = lds + 4 * PAN;       // [dbuf][ks] -> 4 * PAN
  const int tid = threadIdx.x;
  const int wid = tid >> 6, lane = tid & 63;
  const int wr = wid >> 2, wc = wid & 3;    // 2x4 wave grid -> 128x64 per wave
  const int row16 = lane & 15, kgrp = lane >> 4;

  // XCD swizzle: 256 blocks; XCD x owns wg in [32x,32x+32): fixed s, 8 m, 4 n
  int wg = ((blockIdx.x & 7) << 5) | (blockIdx.x >> 3);
  const int s = wg >> 6;
  const int m0 = ((wg >> 2) & 15) * BM, n0 = (wg & 3) * BN;
  const size_t ldb = (size_t)KDIM * 2;
  const size_t kbase = (size_t)s * (KQ * 2);
  const char* Ab = (const char*)A;
  const char* Bb = (const char*)BT;

  f32x4 acc[8][4] = {};

  // Stage one K-half tile (256 rows x 32 elems): 2 gloads/thread.
  // LDS dest linear; global source inverse-swizzled (slot ^= (row>>1)&3).
  auto stageK = [&](const char* Gb, int grow0, unsigned short* slotp, int sl, int ks) {
    size_t kbyte = kbase + (size_t)sl * (BK * 2) + ks * 64;
#pragma unroll
    for (int q = 0; q < 2; ++q) {
      int dd = q * 8192 + tid * 16;         // byte offset in 16 KiB tile
      int row = dd >> 6;                    // 64 B per row
      int sl16 = ((dd >> 4) & 3) ^ ((row >> 1) & 3);
      async_load16(Gb + (size_t)(grow0 + row) * ldb + kbyte + sl16 * 16,
                   (char*)slotp + (q * 8192 + wid * 1024));
    }
  };

  auto rdA = [&](const unsigned short* pan, int mq, bf16x8* dst) {
#pragma unroll
    for (int m = 0; m < 4; ++m) {
      int wrow = wr * 128 + mq * 64 + m * 16 + row16;
      dst[m] = *(const bf16x8*)(pan + wrow * 32 + ((kgrp ^ ((wrow >> 1) & 3)) * 8));
    }
  };
  auto rdB = [&](const unsigned short* pan, bf16x8* dst) {
#pragma unroll
    for (int n = 0; n < 4; ++n) {
      int brow = wc * 64 + n * 16 + row16;
      dst[n] = *(const bf16x8*)(pan + brow * 32 + ((kgrp ^ ((brow >> 1) & 3)) * 8));
    }
  };
  auto mfma16 = [&](int mq, const bf16x8* af, const bf16x8* bfr) {
    __builtin_amdgcn_s_setprio(1);
#pragma unroll
    for (int m = 0; m < 4; ++m)
#pragma unroll
      for (int n = 0; n < 4; ++n)
        acc[mq * 4 + m][n] =
            __builtin_amdgcn_mfma_f32_16x16x32_bf16(af[m], bfr[n], acc[mq * 4 + m][n], 0, 0, 0);
    __builtin_amdgcn_s_setprio(0);
  };

  // Prologue: slice 0's four half-tiles; vmcnt(4) -> Aks0,Bks0 landed.
  stageK(Ab, m0, As + 0 * PAN, 0, 0);
  stageK(Bb, n0, Bs + 0 * PAN, 0, 0);
  stageK(Ab, m0, As + 1 * PAN, 0, 1);
  stageK(Bb, n0, Bs + 1 * PAN, 0, 1);
  asm volatile("s_waitcnt vmcnt(4)" ::: "memory");
  __builtin_amdgcn_s_barrier();

  for (int sl = 0; sl < NSL; ++sl) {
    const int d = sl & 1, dn = d ^ 1;
    const unsigned short* a0 = As + (d * 2 + 0) * PAN;
    const unsigned short* a1 = As + (d * 2 + 1) * PAN;
    const unsigned short* b0 = Bs + (d * 2 + 0) * PAN;
    const unsigned short* b1 = Bs + (d * 2 + 1) * PAN;
    unsigned short* sa0 = As + (dn * 2 + 0) * PAN;
    unsigned short* sa1 = As + (dn * 2 + 1) * PAN;
    unsigned short* sb0 = Bs + (dn * 2 + 0) * PAN;
    unsigned short* sb1 = Bs + (dn * 2 + 1) * PAN;
    const bool pf = (sl + 1 < NSL);
    bf16x8 af[4], bfr[4];

    // ---- ph0: (ks0, mq0) ; stage Aks0(sl+1) ----
    rdB(b0, bfr); rdA(a0, 0, af);
    if (pf) stageK(Ab, m0, sa0, sl + 1, 0);
    __builtin_amdgcn_sched_barrier(0);
    __builtin_amdgcn_s_barrier();
    asm volatile("s_waitcnt lgkmcnt(0)" ::: "memory");
    __builtin_amdgcn_sched_barrier(0);
    mfma16(0, af, bfr);
    __builtin_amdgcn_s_barrier();

    // ---- ph1: (ks0, mq1) ; stage Bks0(sl+1) ; vmcnt protects ks1(sl) ----
    rdA(a0, 1, af);
    if (pf) stageK(Bb, n0, sb0, sl + 1, 0);
    __builtin_amdgcn_sched_barrier(0);
    if (pf) asm volatile("s_waitcnt vmcnt(4)" ::: "memory");
    else    asm volatile("s_waitcnt vmcnt(0)" ::: "memory");
    __builtin_amdgcn_s_barrier();
    asm volatile("s_waitcnt lgkmcnt(0)" ::: "memory");
    __builtin_amdgcn_sched_barrier(0);
    mfma16(1, af, bfr);
    __builtin_amdgcn_s_barrier();

    // ---- ph2: (ks1, mq0) ; stage Aks1(sl+1) ----
    rdB(b1, bfr); rdA(a1, 0, af);
    if (pf) stageK(Ab, m0, sa1, sl + 1, 1);
    __builtin_amdgcn_sched_barrier(0);
    __builtin_amdgcn_s_barrier();
    asm volatile("s_waitcnt lgkmcnt(0)" ::: "memory");
    __builtin_amdgcn_sched_barrier(0);
    mfma16(0, af, bfr);
    __builtin_amdgcn_s_barrier();

    // ---- ph3: (ks1, mq1) ; stage Bks1(sl+1) ; vmcnt protects ks0(sl+1) ----
    rdA(a1, 1, af);
    if (pf) stageK(Bb, n0, sb1, sl + 1, 1);
    __builtin_amdgcn_sched_barrier(0);
    if (pf) asm volatile("s_waitcnt vmcnt(4)" ::: "memory");
    else    asm volatile("s_waitcnt vmcnt(0)" ::: "memory");
    __builtin_amdgcn_s_barrier();
    asm volatile("s_waitcnt lgkmcnt(0)" ::: "memory");
    __builtin_amdgcn_sched_barrier(0);
    mfma16(1, af, bfr);
    __builtin_amdgcn_s_barrier();
  }

  if (s == 3) {
    float* Cb = C + (size_t)(m0 + wr * 128) * OUT_F + n0 + wc * 64;
#pragma unroll
    for (int m = 0; m < 8; ++m)
#pragma unroll
      for (int n = 0; n < 4; ++n)
#pragma unroll
        for (int r = 0; r < 4; ++r)
          Cb[(size_t)(m * 16 + kgrp * 4 + r) * OUT_F + n * 16 + row16] = acc[m][n][r];
  } else {
    unsigned short* Pb = P + (size_t)s * BATCHN * OUT_F
                       + (size_t)(m0 + wr * 128) * OUT_F + n0 + wc * 64;
#pragma unroll
    for (int m = 0; m < 8; ++m)
#pragma unroll
      for (int n = 0; n < 4; ++n)
#pragma unroll
        for (int r = 0; r < 4; ++r)
          Pb[(size_t)(m * 16 + kgrp * 4 + r) * OUT_F + n * 16 + row16] = f2bf(acc[m][n][r]);
  }
}

// ---------------------------------------------------------------------------
// Merge split-K partials (3x bf16) + LayerNorm over last dim (1024), in-place.
// ---------------------------------------------------------------------------
__global__ __launch_bounds__(256) void kan_ln(float* __restrict__ y,
                                              const unsigned short* __restrict__ P,
                                              const float* __restrict__ gamma,
                                              const float* __restrict__ beta) {
  __shared__ float ss[4], ssq[4];
  int tid = threadIdx.x;
  float4* p = (float4*)(y + (size_t)blockIdx.x * OUT_F);
  float4 v = p[tid];
#pragma unroll
  for (int pp = 0; pp < 3; ++pp) {
    const ushort4 pv = ((const ushort4*)(P + (size_t)pp * BATCHN * OUT_F
                                           + (size_t)blockIdx.x * OUT_F))[tid];
    v.x += bf2f(pv.x);
    v.y += bf2f(pv.y);
    v.z += bf2f(pv.z);
    v.w += bf2f(pv.w);
  }
  float s = v.x + v.y + v.z + v.w;
  float q = v.x * v.x + v.y * v.y + v.z * v.z + v.w * v.w;
#pragma unroll
  for (int off = 1; off < 64; off <<= 1) {
    s += __shfl_xor(s, off);
    q += __shfl_xor(q, off);
  }
  if ((tid & 63) == 0) { ss[tid >> 6] = s; ssq[tid >> 6] = q; }
  __syncthreads();
  float S = ss[0] + ss[1] + ss[2] + ss[3];
  float Q = ssq[0] + ssq[1] + ssq[2] + ssq[3];
  float mu  = S * (1.0f / OUT_F);
  float var = Q * (1.0f / OUT_F) - mu * mu;
  float inv = rsqrtf(var + 1e-5f);
  const float4 g  = ((const float4*)gamma)[tid];
  const float4 bt = ((const float4*)beta)[tid];
  float4 o;
  o.x = (v.x - mu) * inv * g.x + bt.x;
  o.y = (v.y - mu) * inv * g.y + bt.y;
  o.z = (v.z - mu) * inv * g.z + bt.z;
  o.w = (v.w - mu) * inv * g.w + bt.w;
  p[tid] = o;
}

extern "C" void kernel_launch(void* const* d_in, const int* in_sizes, int n_in,
                              void* d_out, int out_size, void* d_ws, size_t ws_size,
                              hipStream_t stream) {
  const float* x     = (const float*)d_in[0];
  const float* coef  = (const float*)d_in[1];
  const float* sb    = (const float*)d_in[2];
  const float* ssp   = (const float*)d_in[3];
  const float* gamma = (const float*)d_in[4];
  const float* beta  = (const float*)d_in[5];
  const float* grid  = (const float*)d_in[6];

  const size_t a_elems  = (size_t)BATCHN * KDIM;       // 75.5 MB bf16
  const size_t wt_elems = (size_t)OUT_F * KDIM;        // 18.9 MB bf16
  const size_t p_elems  = (size_t)3 * BATCHN * OUT_F;  // 25.2 MB bf16
  if (ws_size < (a_elems + wt_elems + p_elems) * sizeof(unsigned short)) return;

  unsigned short* A  = (unsigned short*)d_ws;
  unsigned short* WT = A + a_elems;
  unsigned short* P  = WT + wt_elems;
  float* y = (float*)d_out;

  const size_t lds_bytes = 8 * (size_t)PAN * sizeof(unsigned short); // 128 KiB
  static bool attr_set = false;
  if (!attr_set) {
    hipFuncSetAttribute((const void*)kan_gemm,
                        hipFuncAttributeMaxDynamicSharedMemorySize, (int)lds_bytes);
    attr_set = true;
  }

  kan_prep_a<<<dim3((BATCHN * IN_F) / 256), dim3(256), 0, stream>>>(x, grid, A);
  kan_prep_w<<<dim3((IN_F / 32) * (OUT_F / 32)), dim3(256), 0, stream>>>(sb, ssp, coef, WT);
  kan_gemm<<<dim3(4 * (BATCHN / BM) * (OUT_F / BN)), dim3(512), lds_bytes, stream>>>(A, WT, y, P);
  kan_ln<<<dim3(BATCHN), dim3(256), 0, stream>>>(y, P, gamma, beta);
}